// Round 5
// baseline (296.481 us; speedup 1.0000x reference)
//
#include <hip/hip_runtime.h>
#include <hip/hip_bf16.h>
#include <math.h>

// Problem: B=4, N=40962, K=7, C=128
//   sig[b,m]     = sigmoid( sum_d tanh((query[b,m,:]@W1)[d] + b1[d]) * V[d] + bV )
//   score[b,n,k] = sig[b, neigh[n,k]]
//   attn         = score / sum_k score
//   context[b,n] = sum_k attn[b,n,k] * values[b, neigh[n,k], :]
//
// Pipeline (3 dispatches, every stage observable in counters):
//   k0_wconv_vconv : W1 -> fragment-ordered split-bf16 (blocks 0..7)
//                    + values fp32->bf16 compaction (all 2048 blocks)
//   k1_mfma        : PURE MFMA row-score -> sig (zero LDS, no tail)
//   k2_gather_bf16 : bf16 gather + normalize, XCD-batch affinity, 2 rows/group
// bf16 values are essential (R3: fp32 gather = 95us, FETCH 239MB, L3 thrash).

#define CDIM 128
#define KNEIGH 7

typedef __attribute__((ext_vector_type(8))) short bf16x8;
typedef __attribute__((ext_vector_type(4))) short bf16x4;
typedef __attribute__((ext_vector_type(4))) float floatx4;

__device__ inline short f2bf(float x) {
    union { float f; unsigned u; } v; v.f = x;
    unsigned r = (v.u + 0x7fff + ((v.u >> 16) & 1)) >> 16;   // RNE
    return (short)r;
}
__device__ inline float bf2f(short h) {
    union { float f; unsigned u; } v;
    v.u = ((unsigned)(unsigned short)h) << 16; return v.f;
}
__device__ inline float fast_tanh(float x) {
    float e = __expf(2.0f * x);          // inf-safe: e=inf -> 1, e=0 -> -1
    return 1.0f - 2.0f / (e + 1.0f);
}

// ---------------- Kernel 0: W-frag conversion + values compaction ----------
// plane[((t8*4+ks)*64 + lane)*8 + j] = W1[(ks*32+(lane>>4)*8+j)][t8*16+(lane&15)]
// (exactly the B-fragment k1 needs: coalesced 16B/lane, L1/L2-resident 64KB).
// All blocks also stream values fp32 -> bf16 (grid-stride, 2-deep pipeline).
__global__ __launch_bounds__(256) void k0_wconv_vconv(
    const float* __restrict__ W1,      // (128,128) [c][d]
    short* __restrict__ whi,           // 16384 shorts (32 KB)
    short* __restrict__ wlo,           // 16384 shorts (32 KB)
    const float* __restrict__ values,  // (totalRows, 128)
    short* __restrict__ vbf,           // (totalRows, 128) bf16 out (or null)
    int totalRows, int doConv)
{
    const int t = threadIdx.x;

    if (blockIdx.x < 8) {
        const int idx  = blockIdx.x * 256 + t;   // 2048 fragment tuples
        const int lane = idx & 63;
        const int ksf  = (idx >> 6) & 3;
        const int t8   = idx >> 8;
        const int m = lane & 15, q = lane >> 4;
        const int d  = t8 * 16 + m;
        const int c0 = ksf * 32 + q * 8;
        bf16x8 hv, lv;
#pragma unroll
        for (int j = 0; j < 8; ++j) {
            float w = W1[(size_t)(c0 + j) * CDIM + d];
            short h = f2bf(w);
            hv[j] = h;
            lv[j] = f2bf(w - bf2f(h));
        }
        *((bf16x8*)whi + idx) = hv;
        *((bf16x8*)wlo + idx) = lv;
    }

    if (doConv) {
        const int nChunks = totalRows * (CDIM / 8);   // bf16x8 chunks
        const int stride  = gridDim.x * 256;
        int i = blockIdx.x * 256 + t;
        for (; i + stride < nChunks; i += stride * 2) {
            const float4* vp0 = (const float4*)values + (size_t)i * 2;
            const float4* vp1 = (const float4*)values + ((size_t)i + stride) * 2;
            float4 a0 = vp0[0], b0 = vp0[1];
            float4 a1 = vp1[0], b1_ = vp1[1];
            bf16x8 o0, o1;
            o0[0] = f2bf(a0.x); o0[1] = f2bf(a0.y); o0[2] = f2bf(a0.z); o0[3] = f2bf(a0.w);
            o0[4] = f2bf(b0.x); o0[5] = f2bf(b0.y); o0[6] = f2bf(b0.z); o0[7] = f2bf(b0.w);
            o1[0] = f2bf(a1.x); o1[1] = f2bf(a1.y); o1[2] = f2bf(a1.z); o1[3] = f2bf(a1.w);
            o1[4] = f2bf(b1_.x); o1[5] = f2bf(b1_.y); o1[6] = f2bf(b1_.z); o1[7] = f2bf(b1_.w);
            ((bf16x8*)vbf)[i] = o0;
            ((bf16x8*)vbf)[i + stride] = o1;
        }
        for (; i < nChunks; i += stride) {
            const float4* vp = (const float4*)values + (size_t)i * 2;
            float4 a = vp[0];
            float4 b = vp[1];
            bf16x8 o;
            o[0] = f2bf(a.x); o[1] = f2bf(a.y); o[2] = f2bf(a.z); o[3] = f2bf(a.w);
            o[4] = f2bf(b.x); o[5] = f2bf(b.y); o[6] = f2bf(b.z); o[7] = f2bf(b.w);
            ((bf16x8*)vbf)[i] = o;
        }
    }
}

// ---------------- Kernel 1: per-row score precompute (PURE, zero LDS) ------
// 64 rows/block, 16 rows/wave. Per-ks {load -> split-bf16 -> MFMA} (compiler
// pipelines this well; hand-hoisting regressed in R2). No conv tail: this
// round isolates the MFMA+sig phase in the counters.
__global__ __launch_bounds__(256, 4) void k1_mfma(
    const float* __restrict__ query,   // (totalRows, 128)
    const short* __restrict__ whi,     // fragment-ordered hi plane
    const short* __restrict__ wlo,     // fragment-ordered lo plane
    const float* __restrict__ b1,      // (128)
    const float* __restrict__ V,       // (128)
    const float* __restrict__ bV,      // (1)
    float* __restrict__ sig,           // (totalRows)
    int totalRows)
{
    const int t    = threadIdx.x;
    const int wv   = t >> 6;
    const int lane = t & 63;
    const int m    = lane & 15;   // A row / B,D col index
    const int q    = lane >> 4;   // quad
    const long rowBase = (long)blockIdx.x * 64 + wv * 16;

    const bf16x8* WH = (const bf16x8*)whi;
    const bf16x8* WL = (const bf16x8*)wlo;

    floatx4 acc[8];
#pragma unroll
    for (int t8 = 0; t8 < 8; ++t8) acc[t8] = (floatx4){0.f, 0.f, 0.f, 0.f};

#pragma unroll
    for (int ks = 0; ks < 4; ++ks) {
        const int c0 = ks * 32 + q * 8;

        long r = rowBase + m;
        if (r >= totalRows) r = totalRows - 1;   // clamped rows discarded later
        const float* qp = query + (size_t)r * CDIM + c0;
        float4 qa = *(const float4*)qp;
        float4 qb = *(const float4*)(qp + 4);
        float qs[8] = {qa.x, qa.y, qa.z, qa.w, qb.x, qb.y, qb.z, qb.w};
        bf16x8 ah, al;
#pragma unroll
        for (int j = 0; j < 8; ++j) {
            short h = f2bf(qs[j]);
            ah[j] = h;
            al[j] = f2bf(qs[j] - bf2f(h));
        }

#pragma unroll
        for (int t8 = 0; t8 < 8; ++t8) {
            bf16x8 bh = WH[(t8 * 4 + ks) * 64 + lane];
            bf16x8 bl = WL[(t8 * 4 + ks) * 64 + lane];
            acc[t8] = __builtin_amdgcn_mfma_f32_16x16x32_bf16(ah, bh, acc[t8], 0, 0, 0);
            acc[t8] = __builtin_amdgcn_mfma_f32_16x16x32_bf16(al, bh, acc[t8], 0, 0, 0);
            acc[t8] = __builtin_amdgcn_mfma_f32_16x16x32_bf16(ah, bl, acc[t8], 0, 0, 0);
        }
    }

    // ---- epilogue: tanh, dot-V, 16-lane reduce, sigmoid ------------------
    float b1v[8], Vv[8];
#pragma unroll
    for (int t8 = 0; t8 < 8; ++t8) {
        int d = t8 * 16 + m;
        b1v[t8] = b1[d];
        Vv[t8]  = V[d];
    }
    const float bVv = bV[0];
    {
        float p[4] = {0.f, 0.f, 0.f, 0.f};
#pragma unroll
        for (int t8 = 0; t8 < 8; ++t8) {
#pragma unroll
            for (int i = 0; i < 4; ++i) {
                float x = acc[t8][i] + b1v[t8];
                p[i] += fast_tanh(x) * Vv[t8];
            }
        }
#pragma unroll
        for (int mask = 1; mask <= 8; mask <<= 1) {
#pragma unroll
            for (int i = 0; i < 4; ++i) p[i] += __shfl_xor(p[i], mask, 64);
        }
        if (m == 0) {
#pragma unroll
            for (int i = 0; i < 4; ++i) {
                long r = rowBase + q * 4 + i;   // D row = q*4 + reg
                if (r < totalRows)
                    sig[r] = 1.0f / (1.0f + __expf(-(p[i] + bVv)));
            }
        }
    }
}

// ---------------- Kernel 2a: bf16 gather, XCD-batch affinity ---------------
// B=4 assumed. bid&7 = XCD (round-robin dispatch heuristic); XCD pair
// (2k,2k+1) owns batch k. 2 rows per 32-lane group: 14 outstanding 8B
// gathers to hide latency.
__global__ __launch_bounds__(256) void k2_gather_bf16(
    const short* __restrict__ vbf,     // (B*N, 128) bf16
    const int*   __restrict__ neigh,   // (N, 7)
    const float* __restrict__ sig,     // (B*N)
    float* __restrict__ context,       // (B*N, 128)
    float* __restrict__ score,         // (B*N, 7)
    int Nv, int blocksPerBatch)
{
    const int t   = threadIdx.x;
    const int bid = blockIdx.x;
    const int xcd = bid & 7;
    const int b   = xcd >> 1;
    const int nb  = ((bid >> 3) << 1) | (xcd & 1);
    if (nb >= blocksPerBatch) return;
    const int n0 = nb * 16 + ((t >> 5) << 1);
    if (n0 >= Nv) return;
    const bool has1 = (n0 + 1) < Nv;
    const int lane = t & 31;
    const size_t rowOffB = (size_t)b * Nv;

    const int* np0 = neigh + (size_t)n0 * KNEIGH;
    const int* np1 = np0 + KNEIGH;

    int   idx0[KNEIGH], idx1[KNEIGH];
    float s0[KNEIGH],   s1[KNEIGH];
    float ssum0 = 0.f, ssum1 = 0.f;
#pragma unroll
    for (int k = 0; k < KNEIGH; ++k) idx0[k] = np0[k];
#pragma unroll
    for (int k = 0; k < KNEIGH; ++k) idx1[k] = has1 ? np1[k] : idx0[k];
#pragma unroll
    for (int k = 0; k < KNEIGH; ++k) { s0[k] = sig[rowOffB + idx0[k]]; ssum0 += s0[k]; }
#pragma unroll
    for (int k = 0; k < KNEIGH; ++k) { s1[k] = sig[rowOffB + idx1[k]]; ssum1 += s1[k]; }
    const float inv0 = 1.0f / ssum0;
    const float inv1 = 1.0f / ssum1;

    float a0 = 0.f, a1 = 0.f, a2 = 0.f, a3 = 0.f;
    float c0 = 0.f, c1 = 0.f, c2 = 0.f, c3 = 0.f;
#pragma unroll
    for (int k = 0; k < KNEIGH; ++k) {
        bf16x4 v0 = ((const bf16x4*)(vbf + (rowOffB + idx0[k]) * CDIM))[lane];
        bf16x4 v1 = ((const bf16x4*)(vbf + (rowOffB + idx1[k]) * CDIM))[lane];
        float w0 = s0[k] * inv0;
        float w1 = s1[k] * inv1;
        a0 += w0 * bf2f(v0[0]); a1 += w0 * bf2f(v0[1]);
        a2 += w0 * bf2f(v0[2]); a3 += w0 * bf2f(v0[3]);
        c0 += w1 * bf2f(v1[0]); c1 += w1 * bf2f(v1[1]);
        c2 += w1 * bf2f(v1[2]); c3 += w1 * bf2f(v1[3]);
    }
    const size_t g0 = rowOffB + n0;
    floatx4 r0 = (floatx4){a0, a1, a2, a3};
    __builtin_nontemporal_store(r0, (floatx4*)context + g0 * (CDIM / 4) + lane);
    if (has1) {
        floatx4 r1 = (floatx4){c0, c1, c2, c3};
        __builtin_nontemporal_store(r1, (floatx4*)context + (g0 + 1) * (CDIM / 4) + lane);
    }

    // score = s[k] via register select (bit-identical to re-gathering sig).
    if (lane < KNEIGH) {
        float sv = (lane == 1) ? s0[1] : (lane == 2) ? s0[2] : (lane == 3) ? s0[3]
                 : (lane == 4) ? s0[4] : (lane == 5) ? s0[5] : (lane == 6) ? s0[6]
                 : s0[0];
        __builtin_nontemporal_store(sv, score + g0 * KNEIGH + lane);
    } else if (lane >= 8 && lane < 8 + KNEIGH && has1) {
        const int k = lane - 8;
        float sv = (k == 1) ? s1[1] : (k == 2) ? s1[2] : (k == 3) ? s1[3]
                 : (k == 4) ? s1[4] : (k == 5) ? s1[5] : (k == 6) ? s1[6]
                 : s1[0];
        __builtin_nontemporal_store(sv, score + (g0 + 1) * KNEIGH + k);
    }
}

// ---------------- Kernel 2b: fp32 fallback (ws too small / B!=4) ----------
__global__ __launch_bounds__(256) void k2_gather_fp32(
    const float* __restrict__ values,
    const int*   __restrict__ neigh,
    const float* __restrict__ sig,
    float* __restrict__ context,
    float* __restrict__ score,
    int Bv, int Nv)
{
    const int t    = threadIdx.x;
    const int g    = blockIdx.x * 8 + (t >> 5);
    const int lane = t & 31;
    const int total = Bv * Nv;
    if (g >= total) return;
    const int b = g / Nv;
    const int n = g - b * Nv;

    const int* np = neigh + (size_t)n * KNEIGH;
    const size_t rowOffB = (size_t)b * Nv;

    int   idx[KNEIGH];
    float s[KNEIGH];
    float ssum = 0.f;
#pragma unroll
    for (int k = 0; k < KNEIGH; ++k) {
        idx[k] = np[k];
        s[k]   = sig[rowOffB + idx[k]];
        ssum  += s[k];
    }
    const float inv = 1.0f / ssum;

    floatx4 acc = (floatx4){0.f, 0.f, 0.f, 0.f};
#pragma unroll
    for (int k = 0; k < KNEIGH; ++k) {
        const floatx4* vp = (const floatx4*)(values + (rowOffB + idx[k]) * CDIM);
        floatx4 v4 = vp[lane];
        float a = s[k] * inv;
        acc += a * v4;
    }
    __builtin_nontemporal_store(acc, (floatx4*)context + (size_t)g * (CDIM / 4) + lane);

    if (lane < KNEIGH) {
        float sv = (lane == 1) ? s[1] : (lane == 2) ? s[2] : (lane == 3) ? s[3]
                 : (lane == 4) ? s[4] : (lane == 5) ? s[5] : (lane == 6) ? s[6]
                 : s[0];
        __builtin_nontemporal_store(sv, score + (size_t)g * KNEIGH + lane);
    }
}

extern "C" void kernel_launch(void* const* d_in, const int* in_sizes, int n_in,
                              void* d_out, int out_size, void* d_ws, size_t ws_size,
                              hipStream_t stream) {
    const float* query  = (const float*)d_in[0];
    const float* values = (const float*)d_in[1];
    const int*   neigh  = (const int*)d_in[2];
    const float* W1     = (const float*)d_in[3];
    const float* b1     = (const float*)d_in[4];
    const float* V      = (const float*)d_in[5];
    const float* bV     = (const float*)d_in[6];

    const int N = in_sizes[2] / KNEIGH;            // 40962
    const int totalRows = in_sizes[0] / CDIM;      // B*N
    const int B = totalRows / N;                   // 4

    float* context = (float*)d_out;                            // (B*N,128)
    float* score   = (float*)d_out + (size_t)totalRows * CDIM; // (B*N,7)

    // workspace: [whi 32KB][wlo 32KB][sig][vbf]
    short* whi = (short*)d_ws;
    short* wlo = whi + 16384;
    const size_t wOff = 65536;
    float* sig = (float*)((char*)d_ws + wOff);
    size_t sigBytes = (size_t)totalRows * 4;
    size_t vbfOff   = (wOff + sigBytes + 1023) & ~(size_t)1023;
    size_t needBytes = vbfOff + (size_t)totalRows * CDIM * 2;
    const bool useBf16 = (ws_size >= needBytes) && (B == 4);
    short* vbf = (short*)((char*)d_ws + vbfOff);

    int g0 = useBf16 ? 2048 : 8;
    hipLaunchKernelGGL(k0_wconv_vconv, dim3(g0), dim3(256), 0, stream,
                       W1, whi, wlo, values, vbf, totalRows, useBf16 ? 1 : 0);

    int g1 = (totalRows + 63) / 64;                // 2561 blocks
    hipLaunchKernelGGL(k1_mfma, dim3(g1), dim3(256), 0, stream,
                       query, whi, wlo, b1, V, bV, sig, totalRows);

    if (useBf16) {
        int blocksPerBatch = (N + 15) / 16;                // 2561
        int g2 = 8 * ((blocksPerBatch + 1) / 2);           // 10248
        hipLaunchKernelGGL(k2_gather_bf16, dim3(g2), dim3(256), 0, stream,
                           vbf, neigh, sig, context, score, N, blocksPerBatch);
    } else {
        int g2 = (totalRows + 7) / 8;
        hipLaunchKernelGGL(k2_gather_fp32, dim3(g2), dim3(256), 0, stream,
                           values, neigh, sig, context, score, B, N);
    }
}

// Round 6
// 273.864 us; speedup vs baseline: 1.0826x; 1.0826x over previous
//
#include <hip/hip_runtime.h>
#include <hip/hip_bf16.h>
#include <math.h>

// Problem: B=4, N=40962, K=7, C=128
//   sig[b,m]     = sigmoid( sum_d tanh((query[b,m,:]@W1)[d] + b1[d]) * V[d] + bV )
//   score[b,n,k] = sig[b, neigh[n,k]]
//   attn         = score / sum_k score
//   context[b,n] = sum_k attn[b,n,k] * values[b, neigh[n,k], :]
//
// Pipeline:
//   k0_wconv : W1 -> fragment-ordered split-bf16 planes (64KB, one-shot)
//   k1_mfma_conv : W planes staged to LDS once/block (kills the L1-thrash /
//                  L2 hot-line W re-read path: R5 isolated k1-pure at 78us
//                  with ALL pipes <25% busy, occupancy-insensitive)
//                  + fused values fp32->bf16 tail (fusion saves ~20us vs
//                  split: R4 93us fused vs R5 78+~35 split)
//   k2_gather_bf16 : bf16 gather + normalize, XCD-batch affinity, 2 rows/group
// bf16 values essential (R3: fp32 gather = 95us, FETCH 239MB, L3 thrash).

#define CDIM 128
#define KNEIGH 7

typedef __attribute__((ext_vector_type(8))) short bf16x8;
typedef __attribute__((ext_vector_type(4))) short bf16x4;
typedef __attribute__((ext_vector_type(4))) float floatx4;

__device__ inline short f2bf(float x) {
    union { float f; unsigned u; } v; v.f = x;
    unsigned r = (v.u + 0x7fff + ((v.u >> 16) & 1)) >> 16;   // RNE
    return (short)r;
}
__device__ inline float bf2f(short h) {
    union { float f; unsigned u; } v;
    v.u = ((unsigned)(unsigned short)h) << 16; return v.f;
}
__device__ inline float fast_tanh(float x) {
    float e = __expf(2.0f * x);          // inf-safe: e=inf -> 1, e=0 -> -1
    return 1.0f - 2.0f / (e + 1.0f);
}

// ---------------- Kernel 0: W1 -> fragment-ordered split-bf16 planes -------
// plane[((t8*4+ks)*64 + lane)*8 + j] = W1[(ks*32+(lane>>4)*8+j)][t8*16+(lane&15)]
// Exactly the B-fragment each k1 lane needs; linear layout -> LDS copy in k1
// is conflict-free ds_read_b128.
__global__ __launch_bounds__(256) void k0_wconv(
    const float* __restrict__ W1,   // (128,128) [c][d]
    short* __restrict__ whi,        // 16384 shorts (32 KB)
    short* __restrict__ wlo)        // 16384 shorts (32 KB)
{
    const int idx  = blockIdx.x * 256 + threadIdx.x;   // 2048 fragment tuples
    const int lane = idx & 63;
    const int ksf  = (idx >> 6) & 3;
    const int t8   = idx >> 8;
    const int m = lane & 15, q = lane >> 4;
    const int d  = t8 * 16 + m;
    const int c0 = ksf * 32 + q * 8;
    bf16x8 hv, lv;
#pragma unroll
    for (int j = 0; j < 8; ++j) {
        float w = W1[(size_t)(c0 + j) * CDIM + d];
        short h = f2bf(w);
        hv[j] = h;
        lv[j] = f2bf(w - bf2f(h));
    }
    *((bf16x8*)whi + idx) = hv;
    *((bf16x8*)wlo + idx) = lv;
}

// ---------------- Kernel 1: MFMA row-score, W in LDS + fused values conv ---
// 128 rows/block (4 waves x 32 rows), 64KB LDS -> 2 blocks/CU. W planes are
// PRE-CONVERTED (k0), staged with a simple reg-copy (16B/lane chunks), read
// back as linear ds_read_b128 (16B/lane contiguous = conflict-free).
__global__ __launch_bounds__(256, 2) void k1_mfma_conv(
    const float* __restrict__ query,   // (totalRows, 128)
    const short* __restrict__ whi,     // fragment-ordered hi plane
    const short* __restrict__ wlo,     // fragment-ordered lo plane
    const float* __restrict__ b1,      // (128)
    const float* __restrict__ V,       // (128)
    const float* __restrict__ bV,      // (1)
    const float* __restrict__ values,  // (totalRows, 128)
    float* __restrict__ sig,           // (totalRows)
    short* __restrict__ vbf,           // (totalRows, 128) bf16 out (or null)
    int totalRows, int doConv)
{
    __shared__ short Wh[16384];   // 32 KB hi plane (linear, frag-ordered)
    __shared__ short Wl[16384];   // 32 KB lo plane

    const int t    = threadIdx.x;
    const int wv   = t >> 6;
    const int lane = t & 63;
    const int m    = lane & 15;   // A row / B,D col index
    const int q    = lane >> 4;   // quad
    const long rowBase = (long)blockIdx.x * 128 + wv * 32;

    // ---- stage W planes: 2048 16B-chunks per plane, 8 per thread ---------
#pragma unroll
    for (int i = 0; i < 8; ++i) {
        const int c = t + i * 256;              // chunk index
        *(bf16x8*)&Wh[c * 8] = ((const bf16x8*)whi)[c];
        *(bf16x8*)&Wl[c * 8] = ((const bf16x8*)wlo)[c];
    }
    __syncthreads();

    floatx4 acc[2][8];
#pragma unroll
    for (int rt = 0; rt < 2; ++rt)
#pragma unroll
        for (int t8 = 0; t8 < 8; ++t8) acc[rt][t8] = (floatx4){0.f, 0.f, 0.f, 0.f};

#pragma unroll
    for (int ks = 0; ks < 4; ++ks) {
        const int c0 = ks * 32 + q * 8;

        bf16x8 ah[2], al[2];
#pragma unroll
        for (int rt = 0; rt < 2; ++rt) {
            long r = rowBase + rt * 16 + m;
            if (r >= totalRows) r = totalRows - 1;   // clamped rows discarded later
            const float* qp = query + (size_t)r * CDIM + c0;
            float4 qa = *(const float4*)qp;
            float4 qb = *(const float4*)(qp + 4);
            float qs[8] = {qa.x, qa.y, qa.z, qa.w, qb.x, qb.y, qb.z, qb.w};
#pragma unroll
            for (int j = 0; j < 8; ++j) {
                short h = f2bf(qs[j]);
                ah[rt][j] = h;
                al[rt][j] = f2bf(qs[j] - bf2f(h));
            }
        }

#pragma unroll
        for (int t8 = 0; t8 < 8; ++t8) {
            bf16x8 bh = *(const bf16x8*)&Wh[((t8 * 4 + ks) * 64 + lane) * 8];
            bf16x8 bl = *(const bf16x8*)&Wl[((t8 * 4 + ks) * 64 + lane) * 8];
            acc[0][t8] = __builtin_amdgcn_mfma_f32_16x16x32_bf16(ah[0], bh, acc[0][t8], 0, 0, 0);
            acc[1][t8] = __builtin_amdgcn_mfma_f32_16x16x32_bf16(ah[1], bh, acc[1][t8], 0, 0, 0);
            acc[0][t8] = __builtin_amdgcn_mfma_f32_16x16x32_bf16(al[0], bh, acc[0][t8], 0, 0, 0);
            acc[1][t8] = __builtin_amdgcn_mfma_f32_16x16x32_bf16(al[1], bh, acc[1][t8], 0, 0, 0);
            acc[0][t8] = __builtin_amdgcn_mfma_f32_16x16x32_bf16(ah[0], bl, acc[0][t8], 0, 0, 0);
            acc[1][t8] = __builtin_amdgcn_mfma_f32_16x16x32_bf16(ah[1], bl, acc[1][t8], 0, 0, 0);
        }
    }

    // ---- epilogue: tanh, dot-V, 16-lane reduce, sigmoid ------------------
    float b1v[8], Vv[8];
#pragma unroll
    for (int t8 = 0; t8 < 8; ++t8) {
        int d = t8 * 16 + m;
        b1v[t8] = b1[d];
        Vv[t8]  = V[d];
    }
    const float bVv = bV[0];
#pragma unroll
    for (int rt = 0; rt < 2; ++rt) {
        float p[4] = {0.f, 0.f, 0.f, 0.f};
#pragma unroll
        for (int t8 = 0; t8 < 8; ++t8) {
#pragma unroll
            for (int i = 0; i < 4; ++i) {
                float x = acc[rt][t8][i] + b1v[t8];
                p[i] += fast_tanh(x) * Vv[t8];
            }
        }
#pragma unroll
        for (int mask = 1; mask <= 8; mask <<= 1) {
#pragma unroll
            for (int i = 0; i < 4; ++i) p[i] += __shfl_xor(p[i], mask, 64);
        }
        if (m == 0) {
#pragma unroll
            for (int i = 0; i < 4; ++i) {
                long r = rowBase + rt * 16 + q * 4 + i;   // D row = q*4 + reg
                if (r < totalRows)
                    sig[r] = 1.0f / (1.0f + __expf(-(p[i] + bVv)));
            }
        }
    }

    // ---- fused values fp32 -> bf16 compaction (grid-stride, 2-deep) ------
    if (doConv) {
        const int nChunks = totalRows * (CDIM / 8);   // bf16x8 chunks
        const int stride  = gridDim.x * 256;
        int i = blockIdx.x * 256 + t;
        for (; i + stride < nChunks; i += stride * 2) {
            const float4* vp0 = (const float4*)values + (size_t)i * 2;
            const float4* vp1 = (const float4*)values + ((size_t)i + stride) * 2;
            float4 a0 = vp0[0], b0 = vp0[1];
            float4 a1 = vp1[0], b1_ = vp1[1];
            bf16x8 o0, o1;
            o0[0] = f2bf(a0.x); o0[1] = f2bf(a0.y); o0[2] = f2bf(a0.z); o0[3] = f2bf(a0.w);
            o0[4] = f2bf(b0.x); o0[5] = f2bf(b0.y); o0[6] = f2bf(b0.z); o0[7] = f2bf(b0.w);
            o1[0] = f2bf(a1.x); o1[1] = f2bf(a1.y); o1[2] = f2bf(a1.z); o1[3] = f2bf(a1.w);
            o1[4] = f2bf(b1_.x); o1[5] = f2bf(b1_.y); o1[6] = f2bf(b1_.z); o1[7] = f2bf(b1_.w);
            ((bf16x8*)vbf)[i] = o0;
            ((bf16x8*)vbf)[i + stride] = o1;
        }
        for (; i < nChunks; i += stride) {
            const float4* vp = (const float4*)values + (size_t)i * 2;
            float4 a = vp[0];
            float4 b = vp[1];
            bf16x8 o;
            o[0] = f2bf(a.x); o[1] = f2bf(a.y); o[2] = f2bf(a.z); o[3] = f2bf(a.w);
            o[4] = f2bf(b.x); o[5] = f2bf(b.y); o[6] = f2bf(b.z); o[7] = f2bf(b.w);
            ((bf16x8*)vbf)[i] = o;
        }
    }
}

// ---------------- Kernel 2a: bf16 gather, XCD-batch affinity ---------------
// B=4 assumed. bid&7 = XCD (round-robin dispatch heuristic); XCD pair
// (2k,2k+1) owns batch k. 2 rows per 32-lane group: 14 outstanding 8B
// gathers to hide latency.
__global__ __launch_bounds__(256) void k2_gather_bf16(
    const short* __restrict__ vbf,     // (B*N, 128) bf16
    const int*   __restrict__ neigh,   // (N, 7)
    const float* __restrict__ sig,     // (B*N)
    float* __restrict__ context,       // (B*N, 128)
    float* __restrict__ score,         // (B*N, 7)
    int Nv, int blocksPerBatch)
{
    const int t   = threadIdx.x;
    const int bid = blockIdx.x;
    const int xcd = bid & 7;
    const int b   = xcd >> 1;
    const int nb  = ((bid >> 3) << 1) | (xcd & 1);
    if (nb >= blocksPerBatch) return;
    const int n0 = nb * 16 + ((t >> 5) << 1);
    if (n0 >= Nv) return;
    const bool has1 = (n0 + 1) < Nv;
    const int lane = t & 31;
    const size_t rowOffB = (size_t)b * Nv;

    const int* np0 = neigh + (size_t)n0 * KNEIGH;
    const int* np1 = np0 + KNEIGH;

    int   idx0[KNEIGH], idx1[KNEIGH];
    float s0[KNEIGH],   s1[KNEIGH];
    float ssum0 = 0.f, ssum1 = 0.f;
#pragma unroll
    for (int k = 0; k < KNEIGH; ++k) idx0[k] = np0[k];
#pragma unroll
    for (int k = 0; k < KNEIGH; ++k) idx1[k] = has1 ? np1[k] : idx0[k];
#pragma unroll
    for (int k = 0; k < KNEIGH; ++k) { s0[k] = sig[rowOffB + idx0[k]]; ssum0 += s0[k]; }
#pragma unroll
    for (int k = 0; k < KNEIGH; ++k) { s1[k] = sig[rowOffB + idx1[k]]; ssum1 += s1[k]; }
    const float inv0 = 1.0f / ssum0;
    const float inv1 = 1.0f / ssum1;

    float a0 = 0.f, a1 = 0.f, a2 = 0.f, a3 = 0.f;
    float c0 = 0.f, c1 = 0.f, c2 = 0.f, c3 = 0.f;
#pragma unroll
    for (int k = 0; k < KNEIGH; ++k) {
        bf16x4 v0 = ((const bf16x4*)(vbf + (rowOffB + idx0[k]) * CDIM))[lane];
        bf16x4 v1 = ((const bf16x4*)(vbf + (rowOffB + idx1[k]) * CDIM))[lane];
        float w0 = s0[k] * inv0;
        float w1 = s1[k] * inv1;
        a0 += w0 * bf2f(v0[0]); a1 += w0 * bf2f(v0[1]);
        a2 += w0 * bf2f(v0[2]); a3 += w0 * bf2f(v0[3]);
        c0 += w1 * bf2f(v1[0]); c1 += w1 * bf2f(v1[1]);
        c2 += w1 * bf2f(v1[2]); c3 += w1 * bf2f(v1[3]);
    }
    const size_t g0 = rowOffB + n0;
    floatx4 r0 = (floatx4){a0, a1, a2, a3};
    __builtin_nontemporal_store(r0, (floatx4*)context + g0 * (CDIM / 4) + lane);
    if (has1) {
        floatx4 r1 = (floatx4){c0, c1, c2, c3};
        __builtin_nontemporal_store(r1, (floatx4*)context + (g0 + 1) * (CDIM / 4) + lane);
    }

    // score = s[k] via register select (bit-identical to re-gathering sig).
    if (lane < KNEIGH) {
        float sv = (lane == 1) ? s0[1] : (lane == 2) ? s0[2] : (lane == 3) ? s0[3]
                 : (lane == 4) ? s0[4] : (lane == 5) ? s0[5] : (lane == 6) ? s0[6]
                 : s0[0];
        __builtin_nontemporal_store(sv, score + g0 * KNEIGH + lane);
    } else if (lane >= 8 && lane < 8 + KNEIGH && has1) {
        const int k = lane - 8;
        float sv = (k == 1) ? s1[1] : (k == 2) ? s1[2] : (k == 3) ? s1[3]
                 : (k == 4) ? s1[4] : (k == 5) ? s1[5] : (k == 6) ? s1[6]
                 : s1[0];
        __builtin_nontemporal_store(sv, score + (g0 + 1) * KNEIGH + k);
    }
}

// ---------------- Kernel 2b: fp32 fallback (ws too small / B!=4) ----------
__global__ __launch_bounds__(256) void k2_gather_fp32(
    const float* __restrict__ values,
    const int*   __restrict__ neigh,
    const float* __restrict__ sig,
    float* __restrict__ context,
    float* __restrict__ score,
    int Bv, int Nv)
{
    const int t    = threadIdx.x;
    const int g    = blockIdx.x * 8 + (t >> 5);
    const int lane = t & 31;
    const int total = Bv * Nv;
    if (g >= total) return;
    const int b = g / Nv;
    const int n = g - b * Nv;

    const int* np = neigh + (size_t)n * KNEIGH;
    const size_t rowOffB = (size_t)b * Nv;

    int   idx[KNEIGH];
    float s[KNEIGH];
    float ssum = 0.f;
#pragma unroll
    for (int k = 0; k < KNEIGH; ++k) {
        idx[k] = np[k];
        s[k]   = sig[rowOffB + idx[k]];
        ssum  += s[k];
    }
    const float inv = 1.0f / ssum;

    floatx4 acc = (floatx4){0.f, 0.f, 0.f, 0.f};
#pragma unroll
    for (int k = 0; k < KNEIGH; ++k) {
        const floatx4* vp = (const floatx4*)(values + (rowOffB + idx[k]) * CDIM);
        floatx4 v4 = vp[lane];
        float a = s[k] * inv;
        acc += a * v4;
    }
    __builtin_nontemporal_store(acc, (floatx4*)context + (size_t)g * (CDIM / 4) + lane);

    if (lane < KNEIGH) {
        float sv = (lane == 1) ? s[1] : (lane == 2) ? s[2] : (lane == 3) ? s[3]
                 : (lane == 4) ? s[4] : (lane == 5) ? s[5] : (lane == 6) ? s[6]
                 : s[0];
        __builtin_nontemporal_store(sv, score + (size_t)g * KNEIGH + lane);
    }
}

extern "C" void kernel_launch(void* const* d_in, const int* in_sizes, int n_in,
                              void* d_out, int out_size, void* d_ws, size_t ws_size,
                              hipStream_t stream) {
    const float* query  = (const float*)d_in[0];
    const float* values = (const float*)d_in[1];
    const int*   neigh  = (const int*)d_in[2];
    const float* W1     = (const float*)d_in[3];
    const float* b1     = (const float*)d_in[4];
    const float* V      = (const float*)d_in[5];
    const float* bV     = (const float*)d_in[6];

    const int N = in_sizes[2] / KNEIGH;            // 40962
    const int totalRows = in_sizes[0] / CDIM;      // B*N
    const int B = totalRows / N;                   // 4

    float* context = (float*)d_out;                            // (B*N,128)
    float* score   = (float*)d_out + (size_t)totalRows * CDIM; // (B*N,7)

    // workspace: [whi 32KB][wlo 32KB][sig][vbf]
    short* whi = (short*)d_ws;
    short* wlo = whi + 16384;
    const size_t wOff = 65536;
    float* sig = (float*)((char*)d_ws + wOff);
    size_t sigBytes = (size_t)totalRows * 4;
    size_t vbfOff   = (wOff + sigBytes + 1023) & ~(size_t)1023;
    size_t needBytes = vbfOff + (size_t)totalRows * CDIM * 2;
    const bool useBf16 = (ws_size >= needBytes) && (B == 4);
    short* vbf = (short*)((char*)d_ws + vbfOff);

    hipLaunchKernelGGL(k0_wconv, dim3(8), dim3(256), 0, stream, W1, whi, wlo);

    int g1 = (totalRows + 127) / 128;              // 1281 blocks
    hipLaunchKernelGGL(k1_mfma_conv, dim3(g1), dim3(256), 0, stream,
                       query, whi, wlo, b1, V, bV, values, sig, vbf,
                       totalRows, useBf16 ? 1 : 0);

    if (useBf16) {
        int blocksPerBatch = (N + 15) / 16;                // 2561
        int g2 = 8 * ((blocksPerBatch + 1) / 2);           // 10248
        hipLaunchKernelGGL(k2_gather_bf16, dim3(g2), dim3(256), 0, stream,
                           vbf, neigh, sig, context, score, N, blocksPerBatch);
    } else {
        int g2 = (totalRows + 7) / 8;
        hipLaunchKernelGGL(k2_gather_fp32, dim3(g2), dim3(256), 0, stream,
                           values, neigh, sig, context, score, B, N);
    }
}